// Round 4
// baseline (1278.340 us; speedup 1.0000x reference)
//
#include <hip/hip_runtime.h>

// ScaledDotProductAttention: B=4 H=16 S=2048 DK=128, fp32 in, int32 mask.
// Outputs (concatenated in d_out): out (B,H,S,DK) fp32 then weights (B,H,S,S) fp32.
//
// R3: kill per-iteration global-load latency in the O(S^2) loops (R2: latency-bound,
// all pipes <20%).
//  - mask: block-local bitpack. Coalesced 128KB read once per block -> 4KB LDS bit
//    table; phase 1 tests bits via broadcast ds_read_b128 (no global loads in loop).
//  - phase 1: K-tile register prefetch (1-deep software pipeline)
//  - phase 3: P(LDS) + Vt(global) register prefetch (1-deep)
//  - phase 2: 2 rows/iter with b128 LDS reads
//  - prepass: K fp32->fp16 [bh][k][d]; V fp32->fp16 transposed [bh][d][k]

constexpr int Bc = 4, Hc = 16, Sc = 2048, Dc = 128;
constexpr int BHc = Bc * Hc;           // 64
constexpr int QB = 16;                 // q rows per block
constexpr int NQT = Sc / QB;           // 128
constexpr int NBLK = BHc * NQT;        // 8192
constexpr long OUTE = (long)BHc * Sc * Dc;   // out elements (start of weights region)
constexpr long KVE  = (long)BHc * Sc * Dc;   // elements per K/V plane
#define SCALEF 0.088388347648318447f   // 1/sqrt(128)

typedef __attribute__((ext_vector_type(4))) float f32x4;
typedef _Float16 f16x8 __attribute__((ext_vector_type(8)));
typedef unsigned short ushort_t;

static __device__ __forceinline__ f16x8 loadcvt8h(const float* __restrict__ p) {
  float4 a = *(const float4*)p;
  float4 b = *(const float4*)(p + 4);
  f16x8 r;
  r[0] = (_Float16)a.x; r[1] = (_Float16)a.y; r[2] = (_Float16)a.z; r[3] = (_Float16)a.w;
  r[4] = (_Float16)b.x; r[5] = (_Float16)b.y; r[6] = (_Float16)b.z; r[7] = (_Float16)b.w;
  return r;
}

// ---- prepass A: K fp32 -> fp16, same [bh][k][d] layout. 8 elems/thread.
__global__ __launch_bounds__(256)
void kconv_kernel(const float* __restrict__ K, _Float16* __restrict__ Kh) {
  long i = ((long)blockIdx.x * 256 + threadIdx.x) * 8;
  f16x8 v = loadcvt8h(K + i);
  *(f16x8*)(Kh + i) = v;
}

// ---- prepass B: V fp32 [bh][k][d] -> fp16 transposed [bh][d][k].
__global__ __launch_bounds__(256)
void vtrans_kernel(const float* __restrict__ V, _Float16* __restrict__ Vt) {
  __shared__ _Float16 sT[Dc][64 + 2];
  const int bh = blockIdx.x >> 5;
  const int kt = blockIdx.x & 31;
  const int tid = threadIdx.x;
  const float* vb = V + ((long)bh * Sc + kt * 64) * Dc;
  #pragma unroll
  for (int i = 0; i < 8; i++) {
    int e = tid + i * 256;
    int ki = e >> 5;
    int dq = (e & 31) * 4;
    float4 f = *(const float4*)(vb + (long)ki * Dc + dq);
    sT[dq + 0][ki] = (_Float16)f.x;
    sT[dq + 1][ki] = (_Float16)f.y;
    sT[dq + 2][ki] = (_Float16)f.z;
    sT[dq + 3][ki] = (_Float16)f.w;
  }
  __syncthreads();
  #pragma unroll
  for (int i = 0; i < 4; i++) {
    int chunk = tid + i * 256;
    int d = chunk >> 3;
    int kc = (chunk & 7) * 8;
    f16x8 o;
    #pragma unroll
    for (int j = 0; j < 8; j++) o[j] = sT[d][kc + j];
    *(f16x8*)(Vt + ((long)bh * Dc + d) * Sc + kt * 64 + kc) = o;
  }
}

template <bool PRE>
__global__ __launch_bounds__(512, 4)
void sdpa_fused_kernel(const float* __restrict__ Qg, const float* __restrict__ Kg,
                       const float* __restrict__ Vg, const int* __restrict__ Mg,
                       float* __restrict__ Og, const _Float16* __restrict__ Kh,
                       const _Float16* __restrict__ Vt) {
  // P buffer: fp16, swizzled: byte = row*4096 + ((col*2) ^ ((row&7)<<4))
  __shared__ __align__(16) unsigned char sP[QB * Sc * 2];   // 65536 B
  __shared__ __align__(16) unsigned int sMaskW[64][16];      // [word][row], 4 KB
  __shared__ float sRsum[8][QB];
  __shared__ float sRinv[QB];

  const int bid0 = blockIdx.x;
  const int bid  = (bid0 & 7) * (NBLK >> 3) + (bid0 >> 3);   // XCD-chunked swizzle
  const int bh = bid >> 7;
  const int qt = bid & (NQT - 1);

  const int tid  = threadIdx.x;
  const int lane = tid & 63;
  const int wave = tid >> 6;        // 0..7
  const int g = lane >> 4;          // 0..3 (k-group of MFMA operand)
  const int c = lane & 15;          // 0..15 (A row / B col / D col)

  const long mbase = ((long)bh * Sc + (long)qt * QB) * Sc;

  // ---- mask bitpack: thread t loads row t>>5, cols (t&31)*64..+63 (256B coalesced)
  {
    const int row = tid >> 5;
    const int s = tid & 31;
    const int* mp = Mg + mbase + (long)row * Sc + s * 64;
    unsigned w0 = 0, w1 = 0;
    #pragma unroll
    for (int j = 0; j < 8; j++) {
      int4 a = *(const int4*)(mp + j * 4);
      w0 |= (a.x != 0 ? 1u : 0u) << (j * 4)
          | (a.y != 0 ? 1u : 0u) << (j * 4 + 1)
          | (a.z != 0 ? 1u : 0u) << (j * 4 + 2)
          | (a.w != 0 ? 1u : 0u) << (j * 4 + 3);
    }
    #pragma unroll
    for (int j = 8; j < 16; j++) {
      int4 a = *(const int4*)(mp + j * 4);
      const int jj = j - 8;
      w1 |= (a.x != 0 ? 1u : 0u) << (jj * 4)
          | (a.y != 0 ? 1u : 0u) << (jj * 4 + 1)
          | (a.z != 0 ? 1u : 0u) << (jj * 4 + 2)
          | (a.w != 0 ? 1u : 0u) << (jj * 4 + 3);
    }
    sMaskW[s * 2][row] = w0;
    sMaskW[s * 2 + 1][row] = w1;
  }

  // ---- Q A-fragments: lane holds Q[qrow=c][d = ch*32 + g*8 + j]
  f16x8 aq[4];
  {
    const float* qp = Qg + ((long)bh * Sc + (long)qt * QB + c) * Dc + g * 8;
    #pragma unroll
    for (int ch = 0; ch < 4; ch++) aq[ch] = loadcvt8h(qp + ch * 32);
  }
  __syncthreads();  // mask table ready

  float rs[4] = {0.f, 0.f, 0.f, 0.f};

  // ---- Phase 1: S = QK^T/sqrt(dk), mask, exp -> LDS P, row-sum partials.
  // 8 waves stride the 128 k-tiles; K tile prefetched 1-deep into registers.
  f16x8 kc0, kc1, kc2, kc3, kn0, kn1, kn2, kn3;
  {
    if constexpr (PRE) {
      const _Float16* kp = Kh + ((long)bh * Sc + (long)(wave * 16 + c)) * Dc + g * 8;
      kc0 = *(const f16x8*)kp;
      kc1 = *(const f16x8*)(kp + 32);
      kc2 = *(const f16x8*)(kp + 64);
      kc3 = *(const f16x8*)(kp + 96);
    } else {
      const float* kp = Kg + ((long)bh * Sc + (long)(wave * 16 + c)) * Dc + g * 8;
      kc0 = loadcvt8h(kp); kc1 = loadcvt8h(kp + 32);
      kc2 = loadcvt8h(kp + 64); kc3 = loadcvt8h(kp + 96);
    }
  }
  for (int kt = wave; kt < Sc / 16; kt += 8) {
    if (kt + 8 < Sc / 16) {
      if constexpr (PRE) {
        const _Float16* kp = Kh + ((long)bh * Sc + (long)((kt + 8) * 16 + c)) * Dc + g * 8;
        kn0 = *(const f16x8*)kp;
        kn1 = *(const f16x8*)(kp + 32);
        kn2 = *(const f16x8*)(kp + 64);
        kn3 = *(const f16x8*)(kp + 96);
      } else {
        const float* kp = Kg + ((long)bh * Sc + (long)((kt + 8) * 16 + c)) * Dc + g * 8;
        kn0 = loadcvt8h(kp); kn1 = loadcvt8h(kp + 32);
        kn2 = loadcvt8h(kp + 64); kn3 = loadcvt8h(kp + 96);
      }
    }
    // mask words for rows g*4..g*4+3 at word kt>>1 (broadcast b128, conflict-free)
    uint4 mw = *(const uint4*)&sMaskW[kt >> 1][g * 4];
    const unsigned* mwp = (const unsigned*)&mw;

    f32x4 acc = {0.f, 0.f, 0.f, 0.f};
    acc = __builtin_amdgcn_mfma_f32_16x16x32_f16(aq[0], kc0, acc, 0, 0, 0);
    acc = __builtin_amdgcn_mfma_f32_16x16x32_f16(aq[1], kc1, acc, 0, 0, 0);
    acc = __builtin_amdgcn_mfma_f32_16x16x32_f16(aq[2], kc2, acc, 0, 0, 0);
    acc = __builtin_amdgcn_mfma_f32_16x16x32_f16(aq[3], kc3, acc, 0, 0, 0);

    const int col = kt * 16 + c;
    const int bitp = ((kt & 1) << 4) + c;
    #pragma unroll
    for (int r = 0; r < 4; r++) {
      const int row = g * 4 + r;
      float e = ((mwp[r] >> bitp) & 1u) ? __expf(acc[r] * SCALEF) : 0.0f;
      _Float16 eh = (_Float16)e;
      rs[r] += (float)eh;   // accumulate fp16-rounded value so weights sum ~exactly to 1
      *(_Float16*)(sP + row * (Sc * 2) + ((col * 2) ^ ((row & 7) << 4))) = eh;
    }
    kc0 = kn0; kc1 = kn1; kc2 = kn2; kc3 = kn3;
  }

  #pragma unroll
  for (int r = 0; r < 4; r++) {
    float x = rs[r];
    x += __shfl_xor(x, 1);
    x += __shfl_xor(x, 2);
    x += __shfl_xor(x, 4);
    x += __shfl_xor(x, 8);
    rs[r] = x;
  }
  if (c == 0) {
    #pragma unroll
    for (int r = 0; r < 4; r++) sRsum[wave][g * 4 + r] = rs[r];
  }
  __syncthreads();
  if (tid < QB) {
    float t = 0.f;
    #pragma unroll
    for (int w = 0; w < 8; w++) t += sRsum[w][tid];
    sRinv[tid] = (t > 0.0f) ? (1.0f / t) : 0.0f;
  }
  __syncthreads();

  // ---- Phase 2: weights = P * rinv. 2 rows per iter; thread covers 8 cols (b128 read).
  {
    float* wb = Og + OUTE + ((long)bh * Sc + (long)qt * QB) * Sc;
    const int rhalf = tid >> 8;          // 0..1
    const int ct = tid & 255;            // col block: cols ct*8..ct*8+7
    #pragma unroll
    for (int rp = 0; rp < 8; rp++) {
      const int row = rp * 2 + rhalf;
      const float ri = sRinv[row];
      const unsigned char* src = sP + row * (Sc * 2) + ((ct * 16) ^ ((row & 7) << 4));
      f16x8 pv = *(const f16x8*)src;
      float4 w0, w1;
      w0.x = (float)pv[0] * ri; w0.y = (float)pv[1] * ri;
      w0.z = (float)pv[2] * ri; w0.w = (float)pv[3] * ri;
      w1.x = (float)pv[4] * ri; w1.y = (float)pv[5] * ri;
      w1.z = (float)pv[6] * ri; w1.w = (float)pv[7] * ri;
      float* dst = wb + (long)row * Sc + ct * 8;
      *(float4*)dst = w0;
      *(float4*)(dst + 4) = w1;
    }
  }

  float rinv_r[4];
  #pragma unroll
  for (int r = 0; r < 4; r++) rinv_r[r] = sRinv[g * 4 + r];

  // ---- Phase 3: out = P V. A-frag from LDS P; B-frag from Vt; both prefetched 1-deep.
  f32x4 oa = {0.f, 0.f, 0.f, 0.f}, ob2 = {0.f, 0.f, 0.f, 0.f};
  const int nc = wave * 16 + c;     // d column
  if constexpr (PRE) {
    const _Float16* vbase = Vt + ((long)bh * Dc + nc) * Sc + g * 8;
    const unsigned char* abase = sP + c * (Sc * 2);
    const int aswz = (c & 7) << 4;
    f16x8 af0 = *(const f16x8*)(abase + ((0) ^ aswz));
    f16x8 af1 = *(const f16x8*)(abase + ((64 + g * 16) ^ aswz) - (g * 16 ^ aswz) + (g * 16 ^ aswz));
    af1 = *(const f16x8*)(abase + ((64 + g * 16) ^ aswz));
    af0 = *(const f16x8*)(abase + ((g * 16) ^ aswz));
    f16x8 bv0 = *(const f16x8*)(vbase);
    f16x8 bv1 = *(const f16x8*)(vbase + 32);
    f16x8 naf0, naf1, nbv0, nbv1;
    for (int kk = 0; kk < Sc / 32; kk += 2) {
      if (kk + 2 < Sc / 32) {
        naf0 = *(const f16x8*)(abase + (((kk + 2) * 64 + g * 16) ^ aswz));
        naf1 = *(const f16x8*)(abase + (((kk + 3) * 64 + g * 16) ^ aswz));
        nbv0 = *(const f16x8*)(vbase + (kk + 2) * 32);
        nbv1 = *(const f16x8*)(vbase + (kk + 2) * 32 + 32);
      }
      oa  = __builtin_amdgcn_mfma_f32_16x16x32_f16(af0, bv0, oa, 0, 0, 0);
      ob2 = __builtin_amdgcn_mfma_f32_16x16x32_f16(af1, bv1, ob2, 0, 0, 0);
      af0 = naf0; af1 = naf1; bv0 = nbv0; bv1 = nbv1;
    }
  } else {
    for (int kk = 0; kk < Sc / 32; kk++) {
      const int abyte = c * (Sc * 2) + (((kk * 64) + g * 16) ^ ((c & 7) << 4));
      f16x8 af = *(const f16x8*)(sP + abyte);
      const float* vp = Vg + (long)bh * Sc * Dc + (long)(kk * 32 + g * 8) * Dc + nc;
      f16x8 bv;
      #pragma unroll
      for (int j = 0; j < 8; j++) bv[j] = (_Float16)vp[(long)j * Dc];
      oa = __builtin_amdgcn_mfma_f32_16x16x32_f16(af, bv, oa, 0, 0, 0);
    }
  }

  float* ob = Og + ((long)bh * Sc + (long)qt * QB) * Dc;
  #pragma unroll
  for (int r = 0; r < 4; r++) {
    const int row = g * 4 + r;
    ob[(long)row * Dc + nc] = (oa[r] + ob2[r]) * rinv_r[r];
  }
}

extern "C" void kernel_launch(void* const* d_in, const int* in_sizes, int n_in,
                              void* d_out, int out_size, void* d_ws, size_t ws_size,
                              hipStream_t stream) {
  (void)in_sizes; (void)n_in; (void)out_size;
  const float* q = (const float*)d_in[0];
  const float* k = (const float*)d_in[1];
  const float* v = (const float*)d_in[2];
  const int* m = (const int*)d_in[3];
  float* out = (float*)d_out;

  const size_t need = 2UL * KVE * sizeof(_Float16);  // K fp16 + Vt fp16 = 67 MB
  if (d_ws != nullptr && ws_size >= need) {
    _Float16* Kh = (_Float16*)d_ws;
    _Float16* Vt = Kh + KVE;
    hipLaunchKernelGGL(kconv_kernel, dim3((int)(KVE / 8 / 256)), dim3(256), 0, stream, k, Kh);
    hipLaunchKernelGGL(vtrans_kernel, dim3(BHc * 32), dim3(256), 0, stream, v, Vt);
    hipLaunchKernelGGL((sdpa_fused_kernel<true>), dim3(NBLK), dim3(512), 0, stream,
                       q, k, v, m, out, Kh, Vt);
  } else {
    hipLaunchKernelGGL((sdpa_fused_kernel<false>), dim3(NBLK), dim3(512), 0, stream,
                       q, k, v, m, out, nullptr, nullptr);
  }
}

// Round 5
// 1230.728 us; speedup vs baseline: 1.0387x; 1.0387x over previous
//
#include <hip/hip_runtime.h>

// ScaledDotProductAttention: B=4 H=16 S=2048 DK=128, fp32 in, int32 mask.
// Outputs (concatenated in d_out): out (B,H,S,DK) fp32 then weights (B,H,S,S) fp32.
//
// R4: raise memory-level parallelism (R2/R3 latency-bound, all pipes <20%).
//  - phase 1: ping-pong K prefetch (1 tile ahead) + mask dword prefetch (2 ahead), no copies
//  - phase 3: quad MFMA per iter, 1-quad lookahead (4 global + 4 LDS b128 in flight)
//  - weights write FUSED into phase 3 (1 row/iter) so the write stream overlaps the
//    Vt read stream instead of running as a serial store burst
//  - prepass: K fp32->fp16 [bh][k][d]; V fp32->fp16 transposed [bh][d][k]

constexpr int Bc = 4, Hc = 16, Sc = 2048, Dc = 128;
constexpr int BHc = Bc * Hc;           // 64
constexpr int QB = 16;                 // q rows per block
constexpr int NQT = Sc / QB;           // 128
constexpr int NBLK = BHc * NQT;        // 8192
constexpr long OUTE = (long)BHc * Sc * Dc;   // out elements (start of weights region)
constexpr long KVE  = (long)BHc * Sc * Dc;   // elements per K/V plane
#define SCALEF 0.088388347648318447f   // 1/sqrt(128)

typedef __attribute__((ext_vector_type(4))) float f32x4;
typedef _Float16 f16x8 __attribute__((ext_vector_type(8)));
typedef _Float16 f16x4 __attribute__((ext_vector_type(4)));

static __device__ __forceinline__ f16x8 loadcvt8h(const float* __restrict__ p) {
  float4 a = *(const float4*)p;
  float4 b = *(const float4*)(p + 4);
  f16x8 r;
  r[0] = (_Float16)a.x; r[1] = (_Float16)a.y; r[2] = (_Float16)a.z; r[3] = (_Float16)a.w;
  r[4] = (_Float16)b.x; r[5] = (_Float16)b.y; r[6] = (_Float16)b.z; r[7] = (_Float16)b.w;
  return r;
}

// ---- prepass A: K fp32 -> fp16, same [bh][k][d] layout. 8 elems/thread.
__global__ __launch_bounds__(256)
void kconv_kernel(const float* __restrict__ K, _Float16* __restrict__ Kh) {
  long i = ((long)blockIdx.x * 256 + threadIdx.x) * 8;
  f16x8 v = loadcvt8h(K + i);
  *(f16x8*)(Kh + i) = v;
}

// ---- prepass B: V fp32 [bh][k][d] -> fp16 transposed [bh][d][k].
__global__ __launch_bounds__(256)
void vtrans_kernel(const float* __restrict__ V, _Float16* __restrict__ Vt) {
  __shared__ _Float16 sT[Dc][64 + 2];
  const int bh = blockIdx.x >> 5;
  const int kt = blockIdx.x & 31;
  const int tid = threadIdx.x;
  const float* vb = V + ((long)bh * Sc + kt * 64) * Dc;
  #pragma unroll
  for (int i = 0; i < 8; i++) {
    int e = tid + i * 256;
    int ki = e >> 5;
    int dq = (e & 31) * 4;
    float4 f = *(const float4*)(vb + (long)ki * Dc + dq);
    sT[dq + 0][ki] = (_Float16)f.x;
    sT[dq + 1][ki] = (_Float16)f.y;
    sT[dq + 2][ki] = (_Float16)f.z;
    sT[dq + 3][ki] = (_Float16)f.w;
  }
  __syncthreads();
  #pragma unroll
  for (int i = 0; i < 4; i++) {
    int chunk = tid + i * 256;
    int d = chunk >> 3;
    int kc = (chunk & 7) * 8;
    f16x8 o;
    #pragma unroll
    for (int j = 0; j < 8; j++) o[j] = sT[d][kc + j];
    *(f16x8*)(Vt + ((long)bh * Dc + d) * Sc + kt * 64 + kc) = o;
  }
}

template <bool PRE>
__global__ __launch_bounds__(512, 4)
void sdpa_fused_kernel(const float* __restrict__ Qg, const float* __restrict__ Kg,
                       const float* __restrict__ Vg, const int* __restrict__ Mg,
                       float* __restrict__ Og, const _Float16* __restrict__ Kh,
                       const _Float16* __restrict__ Vt) {
  // P buffer: fp16, swizzled: byte = row*4096 + ((col*2) ^ ((row&7)<<4))
  __shared__ __align__(16) unsigned char sP[QB * Sc * 2];   // 65536 B
  __shared__ float sRsum[8][QB];
  __shared__ float sRinv[QB];

  const int bid0 = blockIdx.x;
  const int bid  = (bid0 & 7) * (NBLK >> 3) + (bid0 >> 3);   // XCD-chunked swizzle
  const int bh = bid >> 7;
  const int qt = bid & (NQT - 1);

  const int tid  = threadIdx.x;
  const int lane = tid & 63;
  const int wave = tid >> 6;        // 0..7
  const int g = lane >> 4;          // 0..3 (k-group of MFMA operand)
  const int c = lane & 15;          // 0..15 (A row / B col / D col)

  const long mbase = ((long)bh * Sc + (long)qt * QB) * Sc;

  // ---- Q A-fragments: lane holds Q[qrow=c][d = ch*32 + g*8 + j]
  f16x8 aq[4];
  {
    const float* qp = Qg + ((long)bh * Sc + (long)qt * QB + c) * Dc + g * 8;
    #pragma unroll
    for (int ch = 0; ch < 4; ch++) aq[ch] = loadcvt8h(qp + ch * 32);
  }

  float rs[4] = {0.f, 0.f, 0.f, 0.f};

  // ---- Phase 1: S = QK^T/sqrt(dk), mask, exp -> LDS P, row-sum partials.
  // 8 waves stride the 128 k-tiles (kt = wave + 8t). Ping-pong pipeline:
  // K one body ahead, mask two bodies ahead, no register copies.
  {
    const _Float16* kplane;
    const float* kplane32;
    if constexpr (PRE) kplane = Kh + (long)bh * Sc * Dc;
    else kplane32 = Kg + (long)bh * Sc * Dc;

    f16x8 K0[4], K1[4];
    int M0[4], M1[4];

    auto loadK = [&](f16x8* dst, int kt) {
      if constexpr (PRE) {
        const _Float16* kp = kplane + (long)(kt * 16 + c) * Dc + g * 8;
        dst[0] = *(const f16x8*)kp;
        dst[1] = *(const f16x8*)(kp + 32);
        dst[2] = *(const f16x8*)(kp + 64);
        dst[3] = *(const f16x8*)(kp + 96);
      } else {
        const float* kp = kplane32 + (long)(kt * 16 + c) * Dc + g * 8;
        dst[0] = loadcvt8h(kp);
        dst[1] = loadcvt8h(kp + 32);
        dst[2] = loadcvt8h(kp + 64);
        dst[3] = loadcvt8h(kp + 96);
      }
    };
    auto loadM = [&](int* dst, int kt) {
      const int* mp = Mg + mbase + (long)(kt * 16 + c);
      #pragma unroll
      for (int r = 0; r < 4; r++) dst[r] = mp[(long)(g * 4 + r) * Sc];
    };
    auto body = [&](const f16x8* K, const int* M, int kt) {
      f32x4 acc = {0.f, 0.f, 0.f, 0.f};
      acc = __builtin_amdgcn_mfma_f32_16x16x32_f16(aq[0], K[0], acc, 0, 0, 0);
      acc = __builtin_amdgcn_mfma_f32_16x16x32_f16(aq[1], K[1], acc, 0, 0, 0);
      acc = __builtin_amdgcn_mfma_f32_16x16x32_f16(aq[2], K[2], acc, 0, 0, 0);
      acc = __builtin_amdgcn_mfma_f32_16x16x32_f16(aq[3], K[3], acc, 0, 0, 0);
      const int col = kt * 16 + c;
      #pragma unroll
      for (int r = 0; r < 4; r++) {
        const int row = g * 4 + r;
        float e = (M[r] != 0) ? __expf(acc[r] * SCALEF) : 0.0f;
        _Float16 eh = (_Float16)e;
        rs[r] += (float)eh;   // fp16-rounded so weights sum ~exactly to 1
        *(_Float16*)(sP + row * (Sc * 2) + ((col * 2) ^ ((row & 7) << 4))) = eh;
      }
    };

    loadK(K0, wave);
    loadM(M0, wave);
    loadM(M1, wave + 8);
    for (int t = 0; t < 16; t += 2) {
      const int ktA = wave + t * 8;
      const int ktB = ktA + 8;
      // body A
      loadK(K1, ktB);
      body(K0, M0, ktA);
      if (ktA + 16 < Sc / 16) loadM(M0, ktA + 16);
      // body B
      if (ktA + 16 < Sc / 16) loadK(K0, ktA + 16);
      body(K1, M1, ktB);
      if (ktB + 16 < Sc / 16) loadM(M1, ktB + 16);
    }
  }

  #pragma unroll
  for (int r = 0; r < 4; r++) {
    float x = rs[r];
    x += __shfl_xor(x, 1);
    x += __shfl_xor(x, 2);
    x += __shfl_xor(x, 4);
    x += __shfl_xor(x, 8);
    rs[r] = x;
  }
  if (c == 0) {
    #pragma unroll
    for (int r = 0; r < 4; r++) sRsum[wave][g * 4 + r] = rs[r];
  }
  __syncthreads();
  if (tid < QB) {
    float t = 0.f;
    #pragma unroll
    for (int w = 0; w < 8; w++) t += sRsum[w][tid];
    sRinv[tid] = (t > 0.0f) ? (1.0f / t) : 0.0f;
  }
  __syncthreads();

  float rinv_r[4];
  #pragma unroll
  for (int r = 0; r < 4; r++) rinv_r[r] = sRinv[g * 4 + r];

  // ---- Phase 3 (fused with weights write): out = P V, and one normalized
  // weights row written per iteration (stores overlap Vt loads + MFMA).
  f32x4 ac0 = {0.f, 0.f, 0.f, 0.f}, ac1 = ac0, ac2 = ac0, ac3 = ac0;
  const int nc = wave * 16 + c;     // d column
  float* wb = Og + OUTE + ((long)bh * Sc + (long)qt * QB) * Sc;

  auto wrow = [&](int row) {
    const float ri = sRinv[row];
    const unsigned char* src = sP + row * (Sc * 2) + ((tid * 8) ^ ((row & 7) << 4));
    f16x4 pv = *(const f16x4*)src;
    float4 w;
    w.x = (float)pv[0] * ri;
    w.y = (float)pv[1] * ri;
    w.z = (float)pv[2] * ri;
    w.w = (float)pv[3] * ri;
    *(float4*)(wb + (long)row * Sc + tid * 4) = w;
  };

  if constexpr (PRE) {
    const _Float16* vbase = Vt + ((long)bh * Dc + nc) * Sc + g * 8;
    const unsigned char* abase = sP + c * (Sc * 2);
    const int aswz = (c & 7) << 4;
    f16x8 pA[4], vA[4], pB[4], vB[4];
    auto loadQ = [&](f16x8* pp, f16x8* vv, int it) {
      #pragma unroll
      for (int j = 0; j < 4; j++) {
        const int u = it * 4 + j;
        pp[j] = *(const f16x8*)(abase + ((u * 64 + g * 16) ^ aswz));
        vv[j] = *(const f16x8*)(vbase + u * 32);
      }
    };
    loadQ(pA, vA, 0);
    for (int it = 0; it < 16; it += 2) {
      // body A (quad it)
      loadQ(pB, vB, it + 1);
      wrow(it);
      ac0 = __builtin_amdgcn_mfma_f32_16x16x32_f16(pA[0], vA[0], ac0, 0, 0, 0);
      ac1 = __builtin_amdgcn_mfma_f32_16x16x32_f16(pA[1], vA[1], ac1, 0, 0, 0);
      ac2 = __builtin_amdgcn_mfma_f32_16x16x32_f16(pA[2], vA[2], ac2, 0, 0, 0);
      ac3 = __builtin_amdgcn_mfma_f32_16x16x32_f16(pA[3], vA[3], ac3, 0, 0, 0);
      // body B (quad it+1)
      if (it + 2 < 16) loadQ(pA, vA, it + 2);
      wrow(it + 1);
      ac0 = __builtin_amdgcn_mfma_f32_16x16x32_f16(pB[0], vB[0], ac0, 0, 0, 0);
      ac1 = __builtin_amdgcn_mfma_f32_16x16x32_f16(pB[1], vB[1], ac1, 0, 0, 0);
      ac2 = __builtin_amdgcn_mfma_f32_16x16x32_f16(pB[2], vB[2], ac2, 0, 0, 0);
      ac3 = __builtin_amdgcn_mfma_f32_16x16x32_f16(pB[3], vB[3], ac3, 0, 0, 0);
    }
  } else {
    const float* vplane = Vg + (long)bh * Sc * Dc;
    for (int it = 0; it < 16; it++) {
      wrow(it);
      #pragma unroll
      for (int j = 0; j < 4; j++) {
        const int u = it * 4 + j;
        const int abyte = c * (Sc * 2) + ((u * 64 + g * 16) ^ ((c & 7) << 4));
        f16x8 af = *(const f16x8*)(sP + abyte);
        const float* vp = vplane + (long)(u * 32 + g * 8) * Dc + nc;
        f16x8 bv;
        #pragma unroll
        for (int jj = 0; jj < 8; jj++) bv[jj] = (_Float16)vp[(long)jj * Dc];
        ac0 = __builtin_amdgcn_mfma_f32_16x16x32_f16(af, bv, ac0, 0, 0, 0);
      }
    }
  }

  float* ob = Og + ((long)bh * Sc + (long)qt * QB) * Dc;
  #pragma unroll
  for (int r = 0; r < 4; r++) {
    const int row = g * 4 + r;
    ob[(long)row * Dc + nc] = (ac0[r] + ac1[r] + ac2[r] + ac3[r]) * rinv_r[r];
  }
}

extern "C" void kernel_launch(void* const* d_in, const int* in_sizes, int n_in,
                              void* d_out, int out_size, void* d_ws, size_t ws_size,
                              hipStream_t stream) {
  (void)in_sizes; (void)n_in; (void)out_size;
  const float* q = (const float*)d_in[0];
  const float* k = (const float*)d_in[1];
  const float* v = (const float*)d_in[2];
  const int* m = (const int*)d_in[3];
  float* out = (float*)d_out;

  const size_t need = 2UL * KVE * sizeof(_Float16);  // K fp16 + Vt fp16 = 67 MB
  if (d_ws != nullptr && ws_size >= need) {
    _Float16* Kh = (_Float16*)d_ws;
    _Float16* Vt = Kh + KVE;
    hipLaunchKernelGGL(kconv_kernel, dim3((int)(KVE / 8 / 256)), dim3(256), 0, stream, k, Kh);
    hipLaunchKernelGGL(vtrans_kernel, dim3(BHc * 32), dim3(256), 0, stream, v, Vt);
    hipLaunchKernelGGL((sdpa_fused_kernel<true>), dim3(NBLK), dim3(512), 0, stream,
                       q, k, v, m, out, Kh, Vt);
  } else {
    hipLaunchKernelGGL((sdpa_fused_kernel<false>), dim3(NBLK), dim3(512), 0, stream,
                       q, k, v, m, out, nullptr, nullptr);
  }
}